// Round 8
// baseline (511.503 us; speedup 1.0000x reference)
//
#include <hip/hip_runtime.h>
#include <stdint.h>

typedef unsigned short u16;
typedef unsigned int u32;
typedef __attribute__((ext_vector_type(8))) short bf16x8;
typedef __attribute__((ext_vector_type(4))) float f32x4;
typedef __attribute__((ext_vector_type(2))) u32 u32x2;

__device__ __forceinline__ u16 f2bf(float f) {
  union { float f; u32 u; } x; x.f = f;
  return (u16)((x.u + 0x7FFFu + ((x.u >> 16) & 1u)) >> 16);
}
__device__ __forceinline__ float bf2f(u16 h) {
  union { u32 u; float f; } x; x.u = ((u32)h) << 16; return x.f;
}
__device__ __forceinline__ float bfhi(u32 w) {  // high u16 already in place
  union { u32 u; float f; } x; x.u = w & 0xFFFF0000u; return x.f;
}

// Load 8 consecutive f32, round to bf16 (RTNE), return packed bf16x8.
__device__ __forceinline__ bf16x8 cvt8(const float* __restrict__ p) {
  const f32x4 v0 = *(const f32x4*)p;
  const f32x4 v1 = *(const f32x4*)(p + 4);
  bf16x8 o;
#pragma unroll
  for (int j = 0; j < 4; ++j) {
    o[j] = (short)f2bf(v0[j]);
    o[j + 4] = (short)f2bf(v1[j]);
  }
  return o;
}

// ---- 16-row half-tile transpose through a 4 KiB wave-private Z tile ----
// C/D mapping M1 (HW-verified round-5 probe): value r of lane l is
// D[row=(l>>4)*4+r][col=l&15]. Swizzle: byte ^= (row&7)<<4.
__device__ __forceinline__ void zstore_half(const f32x4 (&accm)[8], u16* zw, int lo, int hi) {
#pragma unroll
  for (int r = 0; r < 4; ++r) {
    const int m = hi * 4 + r;            // 0..15
    const int mb = m * 256;
    const int sw = (m & 7) << 4;
#pragma unroll
    for (int nt = 0; nt < 8; ++nt) {
      const int c = nt * 16 + lo;
      *(u16*)((char*)zw + (mb + ((c * 2) ^ sw))) = f2bf(accm[nt][r]);
    }
  }
}
__device__ __forceinline__ void zload_half(bf16x8 (&A)[4], const u16* zw,
                                           int lo, int hi, int swb) {
  const int mb = lo * 256;               // row = lo, (lo&7) matches swb
#pragma unroll
  for (int kk = 0; kk < 4; ++kk)
    A[kk] = *(const bf16x8*)((const char*)zw + (mb + ((kk * 64 + hi * 16) ^ swb)));
}

// ============ kernel 0: one-time f32 -> bf16 weight conversion ============
// 12288 threads x 8 elems = 2 x 49152.
__global__ void cvt_w_kernel(const float* __restrict__ Wn, const float* __restrict__ We,
                             u16* __restrict__ Wnb, u16* __restrict__ Web) {
  const int t = blockIdx.x * 256 + threadIdx.x;
  if (t < 6144) {
    *(bf16x8*)(Wnb + t * 8) = cvt8(Wn + t * 8);
  } else if (t < 12288) {
    const int u = t - 6144;
    *(bf16x8*)(Web + u * 8) = cvt8(We + u * 8);
  }
}

// ============ kernel 1: Hb[l][n][:] = bf16(X @ Wn[l]^T), barrier-free ======
// Weights read directly global->reg as MFMA B-frags (bf16, L2-hot).
// grid = ceil(N/128), block = 256 (4 waves x 32 rows).
__global__ __launch_bounds__(256, 4) void node_h_kernel(
    const float* __restrict__ X, const u16* __restrict__ Wnb,
    u16* __restrict__ Hb, int N) {
  __shared__ u16 Z[4][16 * 128];  // 16 KiB, wave-private transpose tiles

  const int tid = threadIdx.x;
  const int lane = tid & 63;
  const int wave = tid >> 6;
  const int lo = lane & 15, hi = lane >> 4;
  const int rowbase = blockIdx.x * 128 + wave * 32;
  const int swb = (lo & 7) << 4;
  const f32x4 fzero = {0.f, 0.f, 0.f, 0.f};

  bf16x8 a[2][4];
#pragma unroll
  for (int mt = 0; mt < 2; ++mt) {
    const int r = rowbase + mt * 16 + lo;
    const float* __restrict__ p = X + (size_t)(r < N ? r : 0) * 128;
#pragma unroll
    for (int kk = 0; kk < 4; ++kk)
      a[mt][kk] = cvt8(p + kk * 32 + hi * 8);
  }

  u16* __restrict__ zw = &Z[wave][0];

  for (int layer = 0; layer < 3; ++layer) {
    const u16* __restrict__ Wl = Wnb + layer * 16384;
    f32x4 acc[2][8];
#pragma unroll
    for (int mt = 0; mt < 2; ++mt)
#pragma unroll
      for (int nt = 0; nt < 8; ++nt) acc[mt][nt] = fzero;
#pragma unroll
    for (int kk = 0; kk < 4; ++kk)
#pragma unroll
      for (int nt = 0; nt < 8; ++nt) {
        const bf16x8 w = *(const bf16x8*)(Wl + (nt * 16 + lo) * 128 + kk * 32 + hi * 8);
        acc[0][nt] = __builtin_amdgcn_mfma_f32_16x16x32_bf16(a[0][kk], w, acc[0][nt], 0, 0, 0);
        acc[1][nt] = __builtin_amdgcn_mfma_f32_16x16x32_bf16(a[1][kk], w, acc[1][nt], 0, 0, 0);
      }

    u16* __restrict__ Ho = Hb + (size_t)layer * N * 128;
#pragma unroll
    for (int mt = 0; mt < 2; ++mt) {
      zstore_half(acc[mt], zw, lo, hi);  // wave-private, in-order DS
      bf16x8 t4[4];
      zload_half(t4, zw, lo, hi, swb);
      const int row = rowbase + mt * 16 + lo;
      if (row < N) {
        u16* __restrict__ o = Ho + (size_t)row * 128;
#pragma unroll
        for (int kk = 0; kk < 4; ++kk)
          *(bf16x8*)(o + kk * 32 + hi * 8) = t4[kk];  // 4xhi cover full 64B sectors
      }
    }
  }
}

// ====== kernel 2: per edge, 3x { zlin = z@We^T; z = ELU(h*zlin) }, ==========
// barrier-free; final layer computes the TRANSPOSED gemm D'[feature][edge]
// so stores are full-sector f32x4 runs. grid = ceil(Ne/128), block = 256.
__global__ __launch_bounds__(256, 4) void edge_nobar_kernel(
    const float* __restrict__ E, const u32* __restrict__ SRC,
    const u16* __restrict__ Web, const u16* __restrict__ Hb,
    float* __restrict__ OUT, int Ne, int N) {
  __shared__ u16 Z[4][16 * 128];  // 16 KiB, wave-private transpose tiles

  const int tid = threadIdx.x;
  const int lane = tid & 63;
  const int wave = tid >> 6;
  const int lo = lane & 15, hi = lane >> 4;
  const int rowbase = blockIdx.x * 128 + wave * 32;
  const int swb = (lo & 7) << 4;
  const f32x4 fzero = {0.f, 0.f, 0.f, 0.f};

  // edge_sources dtype sniff: int64 iff first 16 odd u32 words all 0.
  bool is64 = true;
#pragma unroll
  for (int t = 1; t < 32; t += 2) is64 = is64 && (SRC[t] == 0u);

  int row[2], src[2];
  bf16x8 a[2][4];  // z A-frags: lane = edge row lo, k = kk*32 + hi*8 + j
#pragma unroll
  for (int mt = 0; mt < 2; ++mt) {
    row[mt] = rowbase + mt * 16 + lo;
    const int rc = row[mt] < Ne ? row[mt] : 0;
    int s = (int)SRC[is64 ? (2 * rc) : rc];
    src[mt] = (s < 0 || s >= N) ? 0 : s;
    const float* __restrict__ p = E + (size_t)rc * 128;
#pragma unroll
    for (int kk = 0; kk < 4; ++kk)
      a[mt][kk] = cvt8(p + kk * 32 + hi * 8);
  }

  u16* __restrict__ zw = &Z[wave][0];

  // ---- layers 0,1: normal orientation, Z-transpose back to A-frags ----
#pragma unroll
  for (int layer = 0; layer < 2; ++layer) {
    const u16* __restrict__ Wl = Web + layer * 16384;
    f32x4 acc[2][8];
#pragma unroll
    for (int mt = 0; mt < 2; ++mt)
#pragma unroll
      for (int nt = 0; nt < 8; ++nt) acc[mt][nt] = fzero;
#pragma unroll
    for (int kk = 0; kk < 4; ++kk)
#pragma unroll
      for (int nt = 0; nt < 8; ++nt) {
        const bf16x8 w = *(const bf16x8*)(Wl + (nt * 16 + lo) * 128 + kk * 32 + hi * 8);
        acc[0][nt] = __builtin_amdgcn_mfma_f32_16x16x32_bf16(a[0][kk], w, acc[0][nt], 0, 0, 0);
        acc[1][nt] = __builtin_amdgcn_mfma_f32_16x16x32_bf16(a[1][kk], w, acc[1][nt], 0, 0, 0);
      }

    const u16* __restrict__ Hl = Hb + (size_t)layer * N * 128;
#pragma unroll
    for (int mt = 0; mt < 2; ++mt) {
      // h gather issued first: global latency overlaps the DS transpose below
      const u16* __restrict__ hp = Hl + (size_t)src[mt] * 128;
      bf16x8 h[4];
#pragma unroll
      for (int kk = 0; kk < 4; ++kk)
        h[kk] = *(const bf16x8*)(hp + kk * 32 + hi * 8);

      zstore_half(acc[mt], zw, lo, hi);  // wave-private, in-order DS
      bf16x8 zl[4];
      zload_half(zl, zw, lo, hi, swb);
#pragma unroll
      for (int kk = 0; kk < 4; ++kk) {
        bf16x8 o;
#pragma unroll
        for (int j = 0; j < 8; ++j) {
          const float v = bf2f((u16)h[kk][j]) * bf2f((u16)zl[kk][j]);
          const float e = __expf(v) - 1.0f;
          o[j] = (short)f2bf(v > 0.f ? v : e);
        }
        a[mt][kk] = o;
      }
    }
  }

  // ---- layer 2: transposed gemm D'[feature][edge] = We @ z^T ----
  // mfma(w_frag, z_frag): operand0 lo-dim = We output-feature tile row,
  // operand1 lo-dim = edge. Lane holds D'[f=nt*16+hi*4+r][edge=mt*16+lo].
  {
    const u16* __restrict__ Wl = Web + 2 * 16384;
    f32x4 accT[8][2];
#pragma unroll
    for (int nt = 0; nt < 8; ++nt) {
      accT[nt][0] = fzero;
      accT[nt][1] = fzero;
    }
#pragma unroll
    for (int kk = 0; kk < 4; ++kk)
#pragma unroll
      for (int nt = 0; nt < 8; ++nt) {
        const bf16x8 w = *(const bf16x8*)(Wl + (nt * 16 + lo) * 128 + kk * 32 + hi * 8);
        accT[nt][0] = __builtin_amdgcn_mfma_f32_16x16x32_bf16(w, a[0][kk], accT[nt][0], 0, 0, 0);
        accT[nt][1] = __builtin_amdgcn_mfma_f32_16x16x32_bf16(w, a[1][kk], accT[nt][1], 0, 0, 0);
      }

    const u16* __restrict__ Hl = Hb + (size_t)2 * N * 128;
#pragma unroll
    for (int mt = 0; mt < 2; ++mt) {
      if (row[mt] < Ne) {
        const u16* __restrict__ hp = Hl + (size_t)src[mt] * 128;
        float* __restrict__ op = OUT + (size_t)row[mt] * 128;
#pragma unroll
        for (int nt = 0; nt < 8; ++nt) {
          const u32x2 hv = *(const u32x2*)(hp + nt * 16 + hi * 4);  // 4 bf16, 8B
          f32x4 v;
          const float h0 = bf2f((u16)(hv[0] & 0xFFFFu));
          const float h1 = bfhi(hv[0]);
          const float h2 = bf2f((u16)(hv[1] & 0xFFFFu));
          const float h3 = bfhi(hv[1]);
          const float t0 = h0 * accT[nt][mt][0];
          const float t1 = h1 * accT[nt][mt][1];
          const float t2 = h2 * accT[nt][mt][2];
          const float t3 = h3 * accT[nt][mt][3];
          v[0] = t0 > 0.f ? t0 : (__expf(t0) - 1.0f);
          v[1] = t1 > 0.f ? t1 : (__expf(t1) - 1.0f);
          v[2] = t2 > 0.f ? t2 : (__expf(t2) - 1.0f);
          v[3] = t3 > 0.f ? t3 : (__expf(t3) - 1.0f);
          // 4 hi-lanes cover a full 64B sector per instruction
          *(f32x4*)(op + nt * 16 + hi * 4) = v;
        }
      }
    }
  }
}

// ================= fallback: proven round-6 fused kernel =================
__device__ __forceinline__ void stage_w(const float* __restrict__ Wg, u16* lds, int tid) {
#pragma unroll
  for (int i = 0; i < 8; ++i) {
    const int c = tid + i * 256;
    const int n = c >> 4, k8 = c & 15;
    const bf16x8 w = cvt8(Wg + n * 128 + k8 * 8);
    const int b = (n * 256 + k8 * 16) ^ ((n & 7) << 4);
    *(bf16x8*)((char*)lds + b) = w;
  }
}
__device__ __forceinline__ void gemm_pass(const bf16x8 (&A)[2][4], const u16* Wl,
                                          int lo, int hi, int swb,
                                          f32x4 (&acc)[2][8]) {
  const f32x4 fzero = {0.f, 0.f, 0.f, 0.f};
#pragma unroll
  for (int mt = 0; mt < 2; ++mt)
#pragma unroll
    for (int nt = 0; nt < 8; ++nt) acc[mt][nt] = fzero;
#pragma unroll
  for (int kk = 0; kk < 4; ++kk)
#pragma unroll
    for (int nt = 0; nt < 8; ++nt) {
      const int n = nt * 16 + lo;
      const int b = n * 256 + ((kk * 64 + hi * 16) ^ swb);
      const bf16x8 w = *(const bf16x8*)((const char*)Wl + b);
      acc[0][nt] = __builtin_amdgcn_mfma_f32_16x16x32_bf16(A[0][kk], w, acc[0][nt], 0, 0, 0);
      acc[1][nt] = __builtin_amdgcn_mfma_f32_16x16x32_bf16(A[1][kk], w, acc[1][nt], 0, 0, 0);
    }
}
__device__ __forceinline__ void combine_store32(const f32x4 (&aH)[2][8], const f32x4 (&aZ)[2][8],
                                                u16* zw, int lo, int hi) {
#pragma unroll
  for (int mt = 0; mt < 2; ++mt)
#pragma unroll
    for (int r = 0; r < 4; ++r)
#pragma unroll
      for (int nt = 0; nt < 8; ++nt) {
        const float v = aH[mt][nt][r] * aZ[mt][nt][r];
        const float e = __expf(v) - 1.0f;
        const u16 o = f2bf(v > 0.f ? v : e);
        const int m = mt * 16 + hi * 4 + r;
        const int c = nt * 16 + lo;
        *(u16*)((char*)zw + ((m * 256) + ((c * 2) ^ ((m & 7) << 4)))) = o;
      }
}
__device__ __forceinline__ void zload32(bf16x8 (&A)[2][4], const u16* zw,
                                        int lo, int hi, int swb) {
#pragma unroll
  for (int mt = 0; mt < 2; ++mt) {
    const int mb = (mt * 16 + lo) * 256;
#pragma unroll
    for (int kk = 0; kk < 4; ++kk)
      A[mt][kk] = *(const bf16x8*)((const char*)zw + (mb + ((kk * 64 + hi * 16) ^ swb)));
  }
}
__global__ __launch_bounds__(256, 2) void edge_fused_f32out_kernel(
    const float* __restrict__ E, const u32* __restrict__ SRC,
    const float* __restrict__ X,
    const float* __restrict__ Wn, const float* __restrict__ We,
    float* __restrict__ OUT, int Ne, int N) {
  __shared__ u16 Wl[128 * 128];
  __shared__ u16 Z[4][32 * 128];
  const int tid = threadIdx.x;
  const int lane = tid & 63;
  const int wave = tid >> 6;
  const int lo = lane & 15, hi = lane >> 4;
  const int rowbase = blockIdx.x * 128 + wave * 32;
  const int swb = (lo & 7) << 4;
  bool is64 = true;
#pragma unroll
  for (int t = 1; t < 32; t += 2) is64 = is64 && (SRC[t] == 0u);
  int row[2];
  bf16x8 a[2][4], xg[2][4];
#pragma unroll
  for (int mt = 0; mt < 2; ++mt) {
    row[mt] = rowbase + mt * 16 + lo;
    const int rc = row[mt] < Ne ? row[mt] : 0;
    int s = (int)SRC[is64 ? (2 * rc) : rc];
    s = (s < 0 || s >= N) ? 0 : s;
    const float* __restrict__ p = E + (size_t)rc * 128;
    const float* __restrict__ px = X + (size_t)s * 128;
#pragma unroll
    for (int kk = 0; kk < 4; ++kk) {
      a[mt][kk] = cvt8(p + kk * 32 + hi * 8);
      xg[mt][kk] = cvt8(px + kk * 32 + hi * 8);
    }
  }
  u16* __restrict__ zw = &Z[wave][0];
  f32x4 accH[2][8], accZ[2][8];
  for (int layer = 0; layer < 3; ++layer) {
    stage_w(Wn + layer * 16384, Wl, tid);
    __syncthreads();
    gemm_pass(xg, Wl, lo, hi, swb, accH);
    __syncthreads();
    stage_w(We + layer * 16384, Wl, tid);
    __syncthreads();
    gemm_pass(a, Wl, lo, hi, swb, accZ);
    __syncthreads();
    if (layer < 2) {
      combine_store32(accH, accZ, zw, lo, hi);
      zload32(a, zw, lo, hi, swb);
    } else {
#pragma unroll
      for (int mt = 0; mt < 2; ++mt)
#pragma unroll
        for (int r = 0; r < 4; ++r) {
          const int grow = rowbase + mt * 16 + hi * 4 + r;
          if (grow < Ne) {
            float* __restrict__ o = OUT + (size_t)grow * 128;
#pragma unroll
            for (int nt = 0; nt < 8; ++nt) {
              const float v = accH[mt][nt][r] * accZ[mt][nt][r];
              const float e = __expf(v) - 1.0f;
              o[nt * 16 + lo] = (v > 0.f ? v : e);
            }
          }
        }
    }
  }
}

extern "C" void kernel_launch(void* const* d_in, const int* in_sizes, int n_in,
                              void* d_out, int out_size, void* d_ws, size_t ws_size,
                              hipStream_t stream) {
  const float* X   = (const float*)d_in[0];  // input       [N][128] f32
  const u32*   SRC = (const u32*)d_in[1];    // edge_sources[Ne] int64/int32
  const float* E   = (const float*)d_in[2];  // e           [Ne][128] f32
  const float* Wn  = (const float*)d_in[3];  // W_node      [3][128][128] f32
  const float* We  = (const float*)d_in[4];  // W_edge      [3][128][128] f32
  float* OUT = (float*)d_out;                // [Ne][128] f32

  const int N  = in_sizes[0] / 128;
  const int Ne = in_sizes[1];

  const size_t hbElems = (size_t)3 * (size_t)N * 128;
  const size_t need = (hbElems + 2 * 49152) * sizeof(u16);  // Hb + Wnb + Web
  if (ws_size >= need) {
    u16* Hb  = (u16*)d_ws;
    u16* Wnb = Hb + hbElems;   // 16B-aligned: 768*N bytes is a multiple of 16
    u16* Web = Wnb + 49152;
    cvt_w_kernel<<<48, 256, 0, stream>>>(Wn, We, Wnb, Web);
    node_h_kernel<<<(N + 127) / 128, 256, 0, stream>>>(X, Wnb, Hb, N);
    edge_nobar_kernel<<<(Ne + 127) / 128, 256, 0, stream>>>(E, SRC, Web, Hb, OUT, Ne, N);
  } else {
    edge_fused_f32out_kernel<<<(Ne + 127) / 128, 256, 0, stream>>>(E, SRC, X, Wn, We, OUT, Ne, N);
  }
}

// Round 11
// 254.608 us; speedup vs baseline: 2.0090x; 2.0090x over previous
//
#include <hip/hip_runtime.h>
#include <stdint.h>

typedef unsigned short u16;
typedef unsigned int u32;
typedef __attribute__((ext_vector_type(8))) short bf16x8;
typedef __attribute__((ext_vector_type(4))) float f32x4;
typedef __attribute__((ext_vector_type(2))) u32 u32x2;

__device__ __forceinline__ u16 f2bf(float f) {
  union { float f; u32 u; } x; x.f = f;
  return (u16)((x.u + 0x7FFFu + ((x.u >> 16) & 1u)) >> 16);
}
__device__ __forceinline__ float bf2f(u16 h) {
  union { u32 u; float f; } x; x.u = ((u32)h) << 16; return x.f;
}
__device__ __forceinline__ float bfhi(u32 w) {  // high u16 already in place
  union { u32 u; float f; } x; x.u = w & 0xFFFF0000u; return x.f;
}

// Load 8 consecutive f32, round to bf16 (RTNE), return packed bf16x8.
__device__ __forceinline__ bf16x8 cvt8(const float* __restrict__ p) {
  const f32x4 v0 = *(const f32x4*)p;
  const f32x4 v1 = *(const f32x4*)(p + 4);
  bf16x8 o;
#pragma unroll
  for (int j = 0; j < 4; ++j) {
    o[j] = (short)f2bf(v0[j]);
    o[j + 4] = (short)f2bf(v1[j]);
  }
  return o;
}

// Stage a 128x128 f32 weight matrix (row-major W[n][k]) into LDS as bf16 with
// the G4 XOR swizzle: byte ^= (row&7)<<4.  256 threads * 8 chunks * 16B = 32KB.
__device__ __forceinline__ void stage_w(const float* __restrict__ Wg, u16* lds, int tid) {
#pragma unroll
  for (int i = 0; i < 8; ++i) {
    const int c = tid + i * 256;        // bf16 16B-chunk id, 0..2047
    const int n = c >> 4, k8 = c & 15;  // row, 8-elem group within row
    const bf16x8 w = cvt8(Wg + n * 128 + k8 * 8);
    const int b = (n * 256 + k8 * 16) ^ ((n & 7) << 4);
    *(bf16x8*)((char*)lds + b) = w;
  }
}

// One GEMM pass: acc[mt][nt] = A[mt] @ W^T (W staged swizzled in lds).
// A-frag: lane holds row lo (per mt sub-tile), k = kk*32 + hi*8 + j.
__device__ __forceinline__ void gemm_pass(const bf16x8 (&A)[2][4], const u16* Wl,
                                          int lo, int hi, int swb,
                                          f32x4 (&acc)[2][8]) {
  const f32x4 fzero = {0.f, 0.f, 0.f, 0.f};
#pragma unroll
  for (int mt = 0; mt < 2; ++mt)
#pragma unroll
    for (int nt = 0; nt < 8; ++nt) acc[mt][nt] = fzero;
#pragma unroll
  for (int kk = 0; kk < 4; ++kk)
#pragma unroll
    for (int nt = 0; nt < 8; ++nt) {
      const int n = nt * 16 + lo;
      const int b = n * 256 + ((kk * 64 + hi * 16) ^ swb);
      const bf16x8 w = *(const bf16x8*)((const char*)Wl + b);
      acc[0][nt] = __builtin_amdgcn_mfma_f32_16x16x32_bf16(A[0][kk], w, acc[0][nt], 0, 0, 0);
      acc[1][nt] = __builtin_amdgcn_mfma_f32_16x16x32_bf16(A[1][kk], w, acc[1][nt], 0, 0, 0);
    }
}

// ---- 16-row half-tile transpose through a 4 KiB wave-private Z tile ----
// C/D mapping M1 (HW-verified round-5 probe): value r of lane l is
// D[row=(l>>4)*4+r][col=l&15]. Swizzle: byte ^= (row&7)<<4.
__device__ __forceinline__ void zstore_half(const f32x4 (&accm)[8], u16* zw, int lo, int hi) {
#pragma unroll
  for (int r = 0; r < 4; ++r) {
    const int m = hi * 4 + r;            // 0..15
    const int mb = m * 256;
    const int sw = (m & 7) << 4;
#pragma unroll
    for (int nt = 0; nt < 8; ++nt) {
      const int c = nt * 16 + lo;
      *(u16*)((char*)zw + (mb + ((c * 2) ^ sw))) = f2bf(accm[nt][r]);
    }
  }
}
__device__ __forceinline__ void zload_half(bf16x8 (&A)[4], const u16* zw,
                                           int lo, int hi, int swb) {
  const int mb = lo * 256;               // row = lo, (lo&7) matches swb
#pragma unroll
  for (int kk = 0; kk < 4; ++kk)
    A[kk] = *(const bf16x8*)((const char*)zw + (mb + ((kk * 64 + hi * 16) ^ swb)));
}

// ============ kernel 1: Hb[l][n][:] = bf16(X @ Wn[l]^T) ====================
// grid = ceil(N/128), block = 256 (4 waves x 32 rows). (256,2): no spills.
__global__ __launch_bounds__(256, 2) void node_h_kernel(
    const float* __restrict__ X, const float* __restrict__ Wn,
    u16* __restrict__ Hb, int N) {
  __shared__ u16 Wl[128 * 128];   // 32 KiB
  __shared__ u16 Z[4][16 * 128];  // 16 KiB

  const int tid = threadIdx.x;
  const int lane = tid & 63;
  const int wave = tid >> 6;
  const int lo = lane & 15, hi = lane >> 4;
  const int rowbase = blockIdx.x * 128 + wave * 32;
  const int swb = (lo & 7) << 4;

  bf16x8 a[2][4];
#pragma unroll
  for (int mt = 0; mt < 2; ++mt) {
    const int r = rowbase + mt * 16 + lo;
    const float* __restrict__ p = X + (size_t)(r < N ? r : 0) * 128;
#pragma unroll
    for (int kk = 0; kk < 4; ++kk)
      a[mt][kk] = cvt8(p + kk * 32 + hi * 8);
  }

  u16* __restrict__ zw = &Z[wave][0];
  f32x4 acc[2][8];

  for (int layer = 0; layer < 3; ++layer) {
    stage_w(Wn + layer * 16384, Wl, tid);
    __syncthreads();                     // W staged
    gemm_pass(a, Wl, lo, hi, swb, acc);
    __syncthreads();                     // all Wl reads done before next stage

    u16* __restrict__ Ho = Hb + (size_t)layer * N * 128;
#pragma unroll
    for (int mt = 0; mt < 2; ++mt) {
      zstore_half(acc[mt], zw, lo, hi);  // wave-private, in-order DS
      bf16x8 t4[4];
      zload_half(t4, zw, lo, hi, swb);
      const int row = rowbase + mt * 16 + lo;
      if (row < N) {
        u16* __restrict__ o = Ho + (size_t)row * 128;
#pragma unroll
        for (int kk = 0; kk < 4; ++kk)
          *(bf16x8*)(o + kk * 32 + hi * 8) = t4[kk];
      }
    }
  }
}

// ====== kernel 2: per edge, 3x { zlin = z@We^T; z = ELU(h*zlin) } ==========
// (256,2) = 256 regs/wave: acc 64 AGPR + ~140 VGPR live, no scratch spills.
// Cross-layer h prefetch; layer-2 GEMM transposed -> full-sector f32x4 stores.
// grid = ceil(Ne/128), block = 256 (4 waves x 32 edges).
__global__ __launch_bounds__(256, 2) void edge_v9_kernel(
    const float* __restrict__ E, const u32* __restrict__ SRC,
    const float* __restrict__ We, const u16* __restrict__ Hb,
    float* __restrict__ OUT, int Ne, int N) {
  __shared__ u16 Wl[128 * 128];   // 32 KiB
  __shared__ u16 Z[4][16 * 128];  // 16 KiB

  const int tid = threadIdx.x;
  const int lane = tid & 63;
  const int wave = tid >> 6;
  const int lo = lane & 15, hi = lane >> 4;
  const int rowbase = blockIdx.x * 128 + wave * 32;
  const int swb = (lo & 7) << 4;
  const f32x4 fzero = {0.f, 0.f, 0.f, 0.f};

  // edge_sources dtype sniff: int64 iff first 16 odd u32 words all 0.
  bool is64 = true;
#pragma unroll
  for (int t = 1; t < 32; t += 2) is64 = is64 && (SRC[t] == 0u);

  int row[2], src[2];
  bf16x8 a[2][4];  // z A-frags: lane = edge row lo, k = kk*32 + hi*8 + j
#pragma unroll
  for (int mt = 0; mt < 2; ++mt) {
    row[mt] = rowbase + mt * 16 + lo;
    const int rc = row[mt] < Ne ? row[mt] : 0;
    int s = (int)SRC[is64 ? (2 * rc) : rc];
    src[mt] = (s < 0 || s >= N) ? 0 : s;
    const float* __restrict__ p = E + (size_t)rc * 128;
#pragma unroll
    for (int kk = 0; kk < 4; ++kk)
      a[mt][kk] = cvt8(p + kk * 32 + hi * 8);
  }

  u16* __restrict__ zw = &Z[wave][0];
  f32x4 acc[2][8];

  // Prologue: gather h for layer 0 (frag layout).
  bf16x8 hc[2][4];
#pragma unroll
  for (int mt = 0; mt < 2; ++mt) {
    const u16* __restrict__ hp = Hb + (size_t)src[mt] * 128;
#pragma unroll
    for (int kk = 0; kk < 4; ++kk)
      hc[mt][kk] = *(const bf16x8*)(hp + kk * 32 + hi * 8);
  }

  // ---------------- layer 0 ----------------
  stage_w(We, Wl, tid);
  __syncthreads();
  // prefetch h for layer 1 (in flight during GEMM)
  bf16x8 hn[2][4];
#pragma unroll
  for (int mt = 0; mt < 2; ++mt) {
    const u16* __restrict__ hp = Hb + ((size_t)N + src[mt]) * 128;
#pragma unroll
    for (int kk = 0; kk < 4; ++kk)
      hn[mt][kk] = *(const bf16x8*)(hp + kk * 32 + hi * 8);
  }
  gemm_pass(a, Wl, lo, hi, swb, acc);
  __syncthreads();
#pragma unroll
  for (int mt = 0; mt < 2; ++mt) {
    zstore_half(acc[mt], zw, lo, hi);
    bf16x8 zl[4];
    zload_half(zl, zw, lo, hi, swb);
#pragma unroll
    for (int kk = 0; kk < 4; ++kk) {
      bf16x8 o;
#pragma unroll
      for (int j = 0; j < 8; ++j) {
        const float v = bf2f((u16)hc[mt][kk][j]) * bf2f((u16)zl[kk][j]);
        const float e = __expf(v) - 1.0f;
        o[j] = (short)f2bf(v > 0.f ? v : e);
      }
      a[mt][kk] = o;
    }
  }

  // ---------------- layer 1 ----------------
  stage_w(We + 16384, Wl, tid);
  __syncthreads();
  // prefetch h for layer-2 epilogue (transposed slices: 4 bf16 per (mt,nt))
  u32x2 hT[2][8];
#pragma unroll
  for (int mt = 0; mt < 2; ++mt) {
    const u16* __restrict__ hp = Hb + ((size_t)2 * N + src[mt]) * 128;
#pragma unroll
    for (int nt = 0; nt < 8; ++nt)
      hT[mt][nt] = *(const u32x2*)(hp + nt * 16 + hi * 4);
  }
  gemm_pass(a, Wl, lo, hi, swb, acc);
  __syncthreads();
#pragma unroll
  for (int mt = 0; mt < 2; ++mt) {
    zstore_half(acc[mt], zw, lo, hi);
    bf16x8 zl[4];
    zload_half(zl, zw, lo, hi, swb);
#pragma unroll
    for (int kk = 0; kk < 4; ++kk) {
      bf16x8 o;
#pragma unroll
      for (int j = 0; j < 8; ++j) {
        const float v = bf2f((u16)hn[mt][kk][j]) * bf2f((u16)zl[kk][j]);
        const float e = __expf(v) - 1.0f;
        o[j] = (short)f2bf(v > 0.f ? v : e);
      }
      a[mt][kk] = o;
    }
  }

  // ---------------- layer 2: transposed GEMM D'[feat][edge] = We @ z^T ----
  stage_w(We + 2 * 16384, Wl, tid);
  __syncthreads();
  {
    f32x4 accT[8][2];
#pragma unroll
    for (int nt = 0; nt < 8; ++nt) {
      accT[nt][0] = fzero;
      accT[nt][1] = fzero;
    }
#pragma unroll
    for (int kk = 0; kk < 4; ++kk)
#pragma unroll
      for (int nt = 0; nt < 8; ++nt) {
        const int n = nt * 16 + lo;
        const int b = n * 256 + ((kk * 64 + hi * 16) ^ swb);
        const bf16x8 w = *(const bf16x8*)((const char*)Wl + b);
        accT[nt][0] = __builtin_amdgcn_mfma_f32_16x16x32_bf16(w, a[0][kk], accT[nt][0], 0, 0, 0);
        accT[nt][1] = __builtin_amdgcn_mfma_f32_16x16x32_bf16(w, a[1][kk], accT[nt][1], 0, 0, 0);
      }

    // Lane holds D'[f = nt*16 + hi*4 + r][edge = mt*16 + lo]; h from hT.
#pragma unroll
    for (int mt = 0; mt < 2; ++mt) {
      if (row[mt] < Ne) {
        float* __restrict__ op = OUT + (size_t)row[mt] * 128;
#pragma unroll
        for (int nt = 0; nt < 8; ++nt) {
          const u32x2 hv = hT[mt][nt];
          f32x4 v;
          const float h0 = bf2f((u16)(hv[0] & 0xFFFFu));
          const float h1 = bfhi(hv[0]);
          const float h2 = bf2f((u16)(hv[1] & 0xFFFFu));
          const float h3 = bfhi(hv[1]);
          const float t0 = h0 * accT[nt][mt][0];
          const float t1 = h1 * accT[nt][mt][1];
          const float t2 = h2 * accT[nt][mt][2];
          const float t3 = h3 * accT[nt][mt][3];
          v[0] = t0 > 0.f ? t0 : (__expf(t0) - 1.0f);
          v[1] = t1 > 0.f ? t1 : (__expf(t1) - 1.0f);
          v[2] = t2 > 0.f ? t2 : (__expf(t2) - 1.0f);
          v[3] = t3 > 0.f ? t3 : (__expf(t3) - 1.0f);
          // 4 hi-lanes cover a full 64B sector per instruction
          *(f32x4*)(op + nt * 16 + hi * 4) = v;
        }
      }
    }
  }
}

// ================= fallback: proven round-6 fused kernel =================
__device__ __forceinline__ void combine_store32(const f32x4 (&aH)[2][8], const f32x4 (&aZ)[2][8],
                                                u16* zw, int lo, int hi) {
#pragma unroll
  for (int mt = 0; mt < 2; ++mt)
#pragma unroll
    for (int r = 0; r < 4; ++r)
#pragma unroll
      for (int nt = 0; nt < 8; ++nt) {
        const float v = aH[mt][nt][r] * aZ[mt][nt][r];
        const float e = __expf(v) - 1.0f;
        const u16 o = f2bf(v > 0.f ? v : e);
        const int m = mt * 16 + hi * 4 + r;
        const int c = nt * 16 + lo;
        *(u16*)((char*)zw + ((m * 256) + ((c * 2) ^ ((m & 7) << 4)))) = o;
      }
}
__device__ __forceinline__ void zload32(bf16x8 (&A)[2][4], const u16* zw,
                                        int lo, int hi, int swb) {
#pragma unroll
  for (int mt = 0; mt < 2; ++mt) {
    const int mb = (mt * 16 + lo) * 256;
#pragma unroll
    for (int kk = 0; kk < 4; ++kk)
      A[mt][kk] = *(const bf16x8*)((const char*)zw + (mb + ((kk * 64 + hi * 16) ^ swb)));
  }
}
__global__ __launch_bounds__(256, 2) void edge_fused_f32out_kernel(
    const float* __restrict__ E, const u32* __restrict__ SRC,
    const float* __restrict__ X,
    const float* __restrict__ Wn, const float* __restrict__ We,
    float* __restrict__ OUT, int Ne, int N) {
  __shared__ u16 Wl[128 * 128];
  __shared__ u16 Z[4][32 * 128];
  const int tid = threadIdx.x;
  const int lane = tid & 63;
  const int wave = tid >> 6;
  const int lo = lane & 15, hi = lane >> 4;
  const int rowbase = blockIdx.x * 128 + wave * 32;
  const int swb = (lo & 7) << 4;
  bool is64 = true;
#pragma unroll
  for (int t = 1; t < 32; t += 2) is64 = is64 && (SRC[t] == 0u);
  int row[2];
  bf16x8 a[2][4], xg[2][4];
#pragma unroll
  for (int mt = 0; mt < 2; ++mt) {
    row[mt] = rowbase + mt * 16 + lo;
    const int rc = row[mt] < Ne ? row[mt] : 0;
    int s = (int)SRC[is64 ? (2 * rc) : rc];
    s = (s < 0 || s >= N) ? 0 : s;
    const float* __restrict__ p = E + (size_t)rc * 128;
    const float* __restrict__ px = X + (size_t)s * 128;
#pragma unroll
    for (int kk = 0; kk < 4; ++kk) {
      a[mt][kk] = cvt8(p + kk * 32 + hi * 8);
      xg[mt][kk] = cvt8(px + kk * 32 + hi * 8);
    }
  }
  u16* __restrict__ zw = &Z[wave][0];
  f32x4 accH[2][8], accZ[2][8];
  for (int layer = 0; layer < 3; ++layer) {
    stage_w(Wn + layer * 16384, Wl, tid);
    __syncthreads();
    gemm_pass(xg, Wl, lo, hi, swb, accH);
    __syncthreads();
    stage_w(We + layer * 16384, Wl, tid);
    __syncthreads();
    gemm_pass(a, Wl, lo, hi, swb, accZ);
    __syncthreads();
    if (layer < 2) {
      combine_store32(accH, accZ, zw, lo, hi);
      zload32(a, zw, lo, hi, swb);
    } else {
#pragma unroll
      for (int mt = 0; mt < 2; ++mt)
#pragma unroll
        for (int r = 0; r < 4; ++r) {
          const int grow = rowbase + mt * 16 + hi * 4 + r;
          if (grow < Ne) {
            float* __restrict__ o = OUT + (size_t)grow * 128;
#pragma unroll
            for (int nt = 0; nt < 8; ++nt) {
              const float v = accH[mt][nt][r] * accZ[mt][nt][r];
              const float e = __expf(v) - 1.0f;
              o[nt * 16 + lo] = (v > 0.f ? v : e);
            }
          }
        }
    }
  }
}

extern "C" void kernel_launch(void* const* d_in, const int* in_sizes, int n_in,
                              void* d_out, int out_size, void* d_ws, size_t ws_size,
                              hipStream_t stream) {
  const float* X   = (const float*)d_in[0];  // input       [N][128] f32
  const u32*   SRC = (const u32*)d_in[1];    // edge_sources[Ne] int64/int32
  const float* E   = (const float*)d_in[2];  // e           [Ne][128] f32
  const float* Wn  = (const float*)d_in[3];  // W_node      [3][128][128] f32
  const float* We  = (const float*)d_in[4];  // W_edge      [3][128][128] f32
  float* OUT = (float*)d_out;                // [Ne][128] f32

  const int N  = in_sizes[0] / 128;
  const int Ne = in_sizes[1];

  const size_t need = (size_t)3 * (size_t)N * 128 * sizeof(u16);  // 38.4 MB
  if (ws_size >= need) {
    u16* Hb = (u16*)d_ws;
    node_h_kernel<<<(N + 127) / 128, 256, 0, stream>>>(X, Wn, Hb, N);
    edge_v9_kernel<<<(Ne + 127) / 128, 256, 0, stream>>>(E, SRC, We, Hb, OUT, Ne, N);
  } else {
    edge_fused_f32out_kernel<<<(Ne + 127) / 128, 256, 0, stream>>>(E, SRC, X, Wn, We, OUT, Ne, N);
  }
}